// Round 9
// baseline (139.509 us; speedup 1.0000x reference)
//
#include <hip/hip_runtime.h>
#include <hip/hip_bf16.h>
#include <math.h>

#define B_ 256
#define D_ 512
#define C_ 100000
#define BN 128
#define BK 32
#define NTILE 16

#define SCALE_  64.0f
#define ALPHA_  1.2f
// THRESH = cos(pi - 0.5), MM = sin(pi - 0.5) * 0.5
#define THRESH_ (-0.8775825618903728f)
#define MM_     (0.23971276930210156f)
#define COSM_   (0.8775825618903728f)   // cos(0.5)
#define SINM_   (0.4794255386042030f)   // sin(0.5)

typedef __bf16 bf16x8 __attribute__((ext_vector_type(8)));
typedef __bf16 bf16x4 __attribute__((ext_vector_type(4)));
typedef float  f32x4  __attribute__((ext_vector_type(4)));

#define SB()     __builtin_amdgcn_sched_barrier(0)
#define BAR()    __builtin_amdgcn_s_barrier()
#define WAITV(n) asm volatile("s_waitcnt vmcnt(" #n ")" ::: "memory")
#define WAITL0() asm volatile("s_waitcnt lgkmcnt(0)" ::: "memory")

// ---------------------------------------------------------------------------
// prep: normalize input rows -> bf16 in MFMA-A-frag-linear layout
// (1 KiB tiles; tile_idx = rowtile*16 + ktile; lane (b&15)+((l&3)<<4)).
// Also a_lb + canonical labels.
// ---------------------------------------------------------------------------
__global__ void prep_kernel(const float* __restrict__ inp,
                            const int* __restrict__ lab_raw,
                            const float* __restrict__ weight,
                            __bf16* __restrict__ xnf,
                            float* __restrict__ a_lb,
                            int* __restrict__ lab32) {
    const int b = blockIdx.x;
    const int l = threadIdx.x;   // 0..63

    const bool is64 = (lab_raw[1] == 0) & (lab_raw[3] == 0) & (lab_raw[5] == 0) &
                      (lab_raw[7] == 0) & (lab_raw[9] == 0) & (lab_raw[11] == 0) &
                      (lab_raw[13] == 0) & (lab_raw[15] == 0);
    const int lab = is64 ? lab_raw[2 * b] : lab_raw[b];

    const float* ip = inp + b * D_ + l * 8;
    f32x4 v0 = *(const f32x4*)ip;
    f32x4 v1 = *(const f32x4*)(ip + 4);
    float ss = v0.x * v0.x + v0.y * v0.y + v0.z * v0.z + v0.w * v0.w +
               v1.x * v1.x + v1.y * v1.y + v1.z * v1.z + v1.w * v1.w;
#pragma unroll
    for (int m = 1; m < 64; m <<= 1) ss += __shfl_xor(ss, m);
    const float ninv = 1.0f / fmaxf(sqrtf(ss), 1e-12f);

    float xf[8] = {v0.x * ninv, v0.y * ninv, v0.z * ninv, v0.w * ninv,
                   v1.x * ninv, v1.y * ninv, v1.z * ninv, v1.w * ninv};
    bf16x8 xv;
#pragma unroll
    for (int i = 0; i < 8; ++i) xv[i] = (__bf16)xf[i];

    const int tile_idx = (b >> 4) * 16 + (l >> 2);
    const int lf = (b & 15) + ((l & 3) << 4);
    *(bf16x8*)((char*)xnf + tile_idx * 1024 + lf * 16) = xv;

    const float* wp = weight + (size_t)lab * D_ + l * 8;
    f32x4 w0 = *(const f32x4*)wp;
    f32x4 w1 = *(const f32x4*)(wp + 4);
    float wss = w0.x * w0.x + w0.y * w0.y + w0.z * w0.z + w0.w * w0.w +
                w1.x * w1.x + w1.y * w1.y + w1.z * w1.z + w1.w * w1.w;
    float dp = xf[0] * w0.x + xf[1] * w0.y + xf[2] * w0.z + xf[3] * w0.w +
               xf[4] * w1.x + xf[5] * w1.y + xf[6] * w1.z + xf[7] * w1.w;
#pragma unroll
    for (int m = 1; m < 64; m <<= 1) {
        wss += __shfl_xor(wss, m);
        dp  += __shfl_xor(dp, m);
    }
    if (l == 0) {
        const float cos_lb = dp / fmaxf(sqrtf(wss), 1e-12f);
        const float ccl = fminf(fmaxf(cos_lb, -1.0f), 1.0f);
        const float s = sqrtf(fmaxf(0.0f, 1.0f - ccl * ccl));
        const float a1 = ccl * COSM_ - s * SINM_;
        a_lb[b] = (cos_lb > THRESH_) ? a1 : (cos_lb - MM_);
        lab32[b] = lab;
    }
}

// ---------------------------------------------------------------------------
// GEMM + epilogue. 256 thr (4 waves), M=256 x BN=128, 16 K-tiles of BK=32.
// Wave w: rows w*64..+63 x all 128 cols (acc[4][8]); no intra-block A dup ->
// A cache traffic 200 GB total (4x less than R8). R8's proven pipeline:
// homogeneous global_load->VGPR FIFO, per tile [W(t)4, A(t)4, W(t+1)4],
// WAITV(4) retires W(t)+A(t) and leaves W(t+1) in flight across the barrier.
// W cvt f32->bf16 into XOR-swizzled LDS (chunk^=row&3, bijective in 64B row);
// row sumsq from the f32 staging regs (cheap + precise) via wssq LDS.
// ---------------------------------------------------------------------------
__global__ __launch_bounds__(256, 2)
void gemm_kernel(const __bf16* __restrict__ xnf,
                 const float* __restrict__ weight,
                 const float* __restrict__ a_lb,
                 const int* __restrict__ lab32,
                 float* __restrict__ out) {
    __shared__ __align__(16) char wbuf[2][BN * BK * 2];   // 2 x 8 KiB
    __shared__ float wssq[BN];

    const int tid  = threadIdx.x;
    const int lane = tid & 63;
    const int w    = tid >> 6;      // 0..3
    const int n0   = blockIdx.x * BN;
    const int lr   = lane & 15;     // frag row (C column within n-tile)
    const int lk   = lane >> 4;     // frag k-group (0..3)

    f32x4 acc[4][8] = {};
    float wss[4] = {0.f, 0.f, 0.f, 0.f};
    bf16x8 af[4];
    f32x4  wv[2][4];

    // W staging: wave w stages local rows w*32..+31; op j covers 8 rows.
    const int srow = w * 32 + (lane >> 3);   // + 8*j
    const int sc   = lane & 7;               // 16-B chunk within 32-k row
    const char* ab = (const char*)xnf + lane * 16;

    auto issueW = [&](int t, f32x4* v) {
#pragma unroll
        for (int j = 0; j < 4; ++j) {
            int g = n0 + srow + 8 * j;
            g = (g < C_) ? g : (C_ - 1);
            v[j] = *(const f32x4*)(weight + (size_t)g * D_ + t * BK + sc * 4);
        }
    };
    auto issueA = [&](int t) {
#pragma unroll
        for (int m = 0; m < 4; ++m)
            af[m] = *(const bf16x8*)(ab + (size_t)((w * 4 + m) * 16 + t) * 1024);
    };
    auto cvtWrite = [&](const f32x4* v, char* buf) {
#pragma unroll
        for (int j = 0; j < 4; ++j) {
            f32x4 x = v[j];
            wss[j] += x.x * x.x + x.y * x.y + x.z * x.z + x.w * x.w;
            bf16x4 h;
            h[0] = (__bf16)x.x; h[1] = (__bf16)x.y;
            h[2] = (__bf16)x.z; h[3] = (__bf16)x.w;
            const int row = srow + 8 * j;
            const int byte = row * 64 + (((sc >> 1) ^ (row & 3)) << 4) + ((sc & 1) << 3);
            *(bf16x4*)(buf + byte) = h;
        }
    };
    auto compute = [&](const char* buf) {
        bf16x8 bw[8];
#pragma unroll
        for (int n = 0; n < 8; ++n) {
            const int row = n * 16 + lr;
            const int byte = row * 64 + ((lk ^ (row & 3)) << 4);
            bw[n] = *(const bf16x8*)(buf + byte);
        }
#pragma unroll
        for (int m = 0; m < 4; ++m)
#pragma unroll
            for (int n = 0; n < 8; ++n)
                acc[m][n] = __builtin_amdgcn_mfma_f32_16x16x32_bf16(
                    af[m], bw[n], acc[m][n], 0, 0, 0);
    };

    // ---- prologue: FIFO = [W0(4) A0(4) W1(4)]
    issueW(0, wv[0]); SB();
    issueA(0);        SB();
    issueW(1, wv[1]); SB();

#pragma unroll
    for (int t = 0; t < NTILE; ++t) {
        if (t < NTILE - 1) { WAITV(4); } else { WAITV(0); }
        SB();
        cvtWrite(wv[t & 1], wbuf[t & 1]);
        WAITL0(); BAR(); SB();
        compute(wbuf[t & 1]);
        SB();
        if (t < NTILE - 1) { issueA(t + 1); SB(); }
        if (t < NTILE - 2) { issueW(t + 2, wv[t & 1]); SB(); }
    }

    // ---- finish row norms: reduce partials over the 8 staging lanes/row
#pragma unroll
    for (int j = 0; j < 4; ++j) {
        float s = wss[j];
        s += __shfl_xor(s, 1);
        s += __shfl_xor(s, 2);
        s += __shfl_xor(s, 4);
        if ((lane & 7) == 0) wssq[srow + 8 * j] = s;
    }
    __syncthreads();

    // ---- epilogue
    float al_r[16];
    int   lb_r[16];
    const int rb0 = w * 64 + (lk << 2);
#pragma unroll
    for (int m = 0; m < 4; ++m)
#pragma unroll
        for (int j = 0; j < 4; ++j) {
            al_r[m * 4 + j] = a_lb[rb0 + m * 16 + j];
            lb_r[m * 4 + j] = lab32[rb0 + m * 16 + j];
        }

#pragma unroll
    for (int n = 0; n < 8; ++n) {
        const int c = n0 + n * 16 + lr;
        const float winv = 1.0f / fmaxf(sqrtf(wssq[n * 16 + lr]), 1e-12f);
        const bool ok = (c < C_);
#pragma unroll
        for (int m = 0; m < 4; ++m)
#pragma unroll
            for (int j = 0; j < 4; ++j) {
                const float al = al_r[m * 4 + j];
                const float cosv = acc[m][n][j] * winv;
                const float d = cosv - al;
                const float t = ALPHA_ * __expf(-0.5f * d * d);  // SIGMA = 2
                const float o = (c == lb_r[m * 4 + j]) ? al : (t * cosv + t - 1.0f);
                if (ok) out[(size_t)(rb0 + m * 16 + j) * C_ + c] = SCALE_ * o;
            }
    }
}

extern "C" void kernel_launch(void* const* d_in, const int* in_sizes, int n_in,
                              void* d_out, int out_size, void* d_ws, size_t ws_size,
                              hipStream_t stream) {
    const float* inp = (const float*)d_in[0];
    const int*   lab = (const int*)d_in[1];
    const float* w   = (const float*)d_in[2];
    float* out = (float*)d_out;

    char* ws = (char*)d_ws;
    __bf16* xnf  = (__bf16*)ws;                       // 262144 B
    float*  a_lb = (float*)(ws + 262144);             // 1 KiB
    int*    l32  = (int*)(ws + 262144 + 1024);        // 1 KiB

    prep_kernel<<<B_, 64, 0, stream>>>(inp, lab, w, xnf, a_lb, l32);
    gemm_kernel<<<(C_ + BN - 1) / BN, 256, 0, stream>>>(xnf, w, a_lb, l32, out);
}

// Round 10
// 90.336 us; speedup vs baseline: 1.5443x; 1.5443x over previous
//
#include <hip/hip_runtime.h>
#include <hip/hip_bf16.h>
#include <math.h>

#define B_ 256
#define D_ 512
#define C_ 100000
#define BN 128
#define BK 64

#define SCALE_  64.0f
#define ALPHA_  1.2f
// THRESH = cos(pi - 0.5), MM = sin(pi - 0.5) * 0.5
#define THRESH_ (-0.8775825618903728f)
#define MM_     (0.23971276930210156f)
#define COSM_   (0.8775825618903728f)   // cos(0.5)
#define SINM_   (0.4794255386042030f)   // sin(0.5)

typedef __bf16 bf16x8 __attribute__((ext_vector_type(8)));
typedef __bf16 bf16x4 __attribute__((ext_vector_type(4)));
typedef float  f32x4  __attribute__((ext_vector_type(4)));

#define SB()     __builtin_amdgcn_sched_barrier(0)
#define BAR()    __builtin_amdgcn_s_barrier()
#define WAITV(n) asm volatile("s_waitcnt vmcnt(" #n ")" ::: "memory")
#define WAITL0() asm volatile("s_waitcnt lgkmcnt(0)" ::: "memory")

// ---------------------------------------------------------------------------
// prep: normalize input rows -> bf16 in MFMA-A-frag-linear layout
// (1 KiB tiles; tile_idx = rowtile*16 + ktile; lane (b&15)+((l&3)<<4)).
// Also a_lb + canonical labels.
// ---------------------------------------------------------------------------
__global__ void prep_kernel(const float* __restrict__ inp,
                            const int* __restrict__ lab_raw,
                            const float* __restrict__ weight,
                            __bf16* __restrict__ xnf,
                            float* __restrict__ a_lb,
                            int* __restrict__ lab32) {
    const int b = blockIdx.x;
    const int l = threadIdx.x;   // 0..63

    const bool is64 = (lab_raw[1] == 0) & (lab_raw[3] == 0) & (lab_raw[5] == 0) &
                      (lab_raw[7] == 0) & (lab_raw[9] == 0) & (lab_raw[11] == 0) &
                      (lab_raw[13] == 0) & (lab_raw[15] == 0);
    const int lab = is64 ? lab_raw[2 * b] : lab_raw[b];

    const float* ip = inp + b * D_ + l * 8;
    f32x4 v0 = *(const f32x4*)ip;
    f32x4 v1 = *(const f32x4*)(ip + 4);
    float ss = v0.x * v0.x + v0.y * v0.y + v0.z * v0.z + v0.w * v0.w +
               v1.x * v1.x + v1.y * v1.y + v1.z * v1.z + v1.w * v1.w;
#pragma unroll
    for (int m = 1; m < 64; m <<= 1) ss += __shfl_xor(ss, m);
    const float ninv = 1.0f / fmaxf(sqrtf(ss), 1e-12f);

    float xf[8] = {v0.x * ninv, v0.y * ninv, v0.z * ninv, v0.w * ninv,
                   v1.x * ninv, v1.y * ninv, v1.z * ninv, v1.w * ninv};
    bf16x8 xv;
#pragma unroll
    for (int i = 0; i < 8; ++i) xv[i] = (__bf16)xf[i];

    const int tile_idx = (b >> 4) * 16 + (l >> 2);
    const int lf = (b & 15) + ((l & 3) << 4);
    *(bf16x8*)((char*)xnf + tile_idx * 1024 + lf * 16) = xv;

    const float* wp = weight + (size_t)lab * D_ + l * 8;
    f32x4 w0 = *(const f32x4*)wp;
    f32x4 w1 = *(const f32x4*)(wp + 4);
    float wss = w0.x * w0.x + w0.y * w0.y + w0.z * w0.z + w0.w * w0.w +
                w1.x * w1.x + w1.y * w1.y + w1.z * w1.z + w1.w * w1.w;
    float dp = xf[0] * w0.x + xf[1] * w0.y + xf[2] * w0.z + xf[3] * w0.w +
               xf[4] * w1.x + xf[5] * w1.y + xf[6] * w1.z + xf[7] * w1.w;
#pragma unroll
    for (int m = 1; m < 64; m <<= 1) {
        wss += __shfl_xor(wss, m);
        dp  += __shfl_xor(dp, m);
    }
    if (l == 0) {
        const float cos_lb = dp / fmaxf(sqrtf(wss), 1e-12f);
        const float ccl = fminf(fmaxf(cos_lb, -1.0f), 1.0f);
        const float s = sqrtf(fmaxf(0.0f, 1.0f - ccl * ccl));
        const float a1 = ccl * COSM_ - s * SINM_;
        a_lb[b] = (cos_lb > THRESH_) ? a1 : (cos_lb - MM_);
        lab32[b] = lab;
    }
}

// ---------------------------------------------------------------------------
// GEMM + epilogue. 512 thr (8 waves), M=256 x BN=128, 8 K-tiles of BK=64.
// Wave w: A rows w*32..+31 x all 128 cols -> acc[2][8] = 64 VGPR (no spill).
// A-traffic/block = full A (256 KB, L2-resident) but only 782 blocks = 200 GB
// (4x less than R8). R8's proven homogeneous counted-vmcnt pipeline, depth 2:
// per tile FIFO [A(t)4, W(t)4 | ...], WAITV(8); W(t+2) issued before compute,
// A(t+2) after (WAR on af). Named triple wv / double af buffers, macro-
// expanded literal indices only (R9's spill was array-of-buffer indexing).
// W cvt f32->bf16 into XOR-swizzled LDS (chunk^=row&7 at 16B granularity);
// row sumsq from f32 staging regs, reduced over the row's 16 lanes at end.
// ---------------------------------------------------------------------------
__global__ __launch_bounds__(512, 2)
void gemm_kernel(const __bf16* __restrict__ xnf,
                 const float* __restrict__ weight,
                 const float* __restrict__ a_lb,
                 const int* __restrict__ lab32,
                 float* __restrict__ out) {
    __shared__ __align__(16) char wbuf0[BN * BK * 2];   // 16 KiB
    __shared__ __align__(16) char wbuf1[BN * BK * 2];   // 16 KiB
    __shared__ float wssq[BN];

    const int tid  = threadIdx.x;
    const int lane = tid & 63;
    const int w    = tid >> 6;      // 0..7
    const int n0   = blockIdx.x * BN;
    const int lr   = lane & 15;     // frag row (C column within n-tile)
    const int lk   = lane >> 4;     // frag k-group (0..3)

    f32x4 acc[2][8] = {};
    float ssq[4] = {0.f, 0.f, 0.f, 0.f};
    f32x4  wvA[4], wvB[4], wvC[4];
    bf16x8 afA[2][2], afB[2][2];

    // W staging geometry: wave w stages rows w*16..+15; op j covers 4 rows.
    const int srow0 = w * 16 + (lane >> 4);   // + 4*j
    const int sc16  = lane & 15;              // f32x4 chunk (16 per 64-k row)

#define ISSUEW(t, WV) do {                                                     \
    _Pragma("unroll")                                                          \
    for (int j = 0; j < 4; ++j) {                                              \
        int g = n0 + srow0 + 4 * j;                                            \
        g = (g < C_) ? g : (C_ - 1);                                           \
        WV[j] = *(const f32x4*)(weight + (size_t)g * D_ + (t) * BK + sc16 * 4);\
    } } while (0)

#define ISSUEA(t, AF) do {                                                     \
    _Pragma("unroll")                                                          \
    for (int m = 0; m < 2; ++m)                                                \
        _Pragma("unroll")                                                      \
        for (int ks = 0; ks < 2; ++ks)                                         \
            AF[m][ks] = *(const bf16x8*)((const char*)xnf +                    \
                (((2 * w + m) * 16 + 2 * (t) + ks) << 10) + lane * 16);        \
    } while (0)

#define CVTW(WV, BUF) do {                                                     \
    _Pragma("unroll")                                                          \
    for (int j = 0; j < 4; ++j) {                                              \
        f32x4 x = WV[j];                                                       \
        ssq[j] += x.x * x.x + x.y * x.y + x.z * x.z + x.w * x.w;               \
        bf16x4 h;                                                              \
        h[0] = (__bf16)x.x; h[1] = (__bf16)x.y;                                \
        h[2] = (__bf16)x.z; h[3] = (__bf16)x.w;                                \
        const int row = srow0 + 4 * j;                                         \
        const int byte = row * 128 + (((sc16 >> 1) ^ (row & 7)) << 4)          \
                         + ((sc16 & 1) << 3);                                  \
        *(bf16x4*)((BUF) + byte) = h;                                          \
    } } while (0)

#define COMPUTE(BUF, AF) do {                                                  \
    _Pragma("unroll")                                                          \
    for (int ks = 0; ks < 2; ++ks) {                                           \
        _Pragma("unroll")                                                      \
        for (int n = 0; n < 8; ++n) {                                          \
            const int row = n * 16 + lr;                                       \
            const int byte = row * 128 + (((ks * 4 + lk) ^ (row & 7)) << 4);   \
            bf16x8 bw = *(const bf16x8*)((BUF) + byte);                        \
            acc[0][n] = __builtin_amdgcn_mfma_f32_16x16x32_bf16(               \
                AF[0][ks], bw, acc[0][n], 0, 0, 0);                            \
            acc[1][n] = __builtin_amdgcn_mfma_f32_16x16x32_bf16(               \
                AF[1][ks], bw, acc[1][n], 0, 0, 0);                            \
        }                                                                      \
    } } while (0)

    // ---- prologue: FIFO = [A0(4) W0(4) A1(4) W1(4)]
    ISSUEA(0, afA); SB();
    ISSUEW(0, wvA); SB();
    ISSUEA(1, afB); SB();
    ISSUEW(1, wvB); SB();

#define TILE(t, WVCUR, WVNXT2, AFCUR, BUFC)                                    \
    WAITV(8); SB();                                                            \
    CVTW(WVCUR, BUFC);                                                         \
    WAITL0(); BAR(); SB();                                                     \
    if ((t) + 2 < 8) { ISSUEW((t) + 2, WVNXT2); SB(); }                        \
    COMPUTE(BUFC, AFCUR);                                                      \
    SB();                                                                      \
    if ((t) + 2 < 8) { ISSUEA((t) + 2, AFCUR); SB(); }

    TILE(0, wvA, wvC, afA, wbuf0)
    TILE(1, wvB, wvA, afB, wbuf1)
    TILE(2, wvC, wvB, afA, wbuf0)
    TILE(3, wvA, wvC, afB, wbuf1)
    TILE(4, wvB, wvA, afA, wbuf0)
    TILE(5, wvC, wvB, afB, wbuf1)

    // t=6: nothing left to issue; t=7 drains
    WAITV(8); SB();
    CVTW(wvA, wbuf0);
    WAITL0(); BAR(); SB();
    COMPUTE(wbuf0, afA);
    SB();
    WAITV(0); SB();
    CVTW(wvB, wbuf1);
    WAITL0(); BAR(); SB();
    COMPUTE(wbuf1, afB);

    // ---- finish row norms: reduce over the 16 lanes owning each row
#pragma unroll
    for (int j = 0; j < 4; ++j) {
        float s = ssq[j];
        s += __shfl_xor(s, 1);
        s += __shfl_xor(s, 2);
        s += __shfl_xor(s, 4);
        s += __shfl_xor(s, 8);
        if (sc16 == 0) wssq[srow0 + 4 * j] = s;
    }
    __syncthreads();

    // ---- epilogue
    float al_r[8];
    int   lb_r[8];
    const int rb0 = w * 32 + (lk << 2);
#pragma unroll
    for (int m = 0; m < 2; ++m)
#pragma unroll
        for (int j = 0; j < 4; ++j) {
            al_r[m * 4 + j] = a_lb[rb0 + m * 16 + j];
            lb_r[m * 4 + j] = lab32[rb0 + m * 16 + j];
        }

#pragma unroll
    for (int n = 0; n < 8; ++n) {
        const int c = n0 + n * 16 + lr;
        const float winv = 1.0f / fmaxf(sqrtf(wssq[n * 16 + lr]), 1e-12f);
        const bool ok = (c < C_);
#pragma unroll
        for (int m = 0; m < 2; ++m)
#pragma unroll
            for (int j = 0; j < 4; ++j) {
                const float al = al_r[m * 4 + j];
                const float cosv = acc[m][n][j] * winv;
                const float d = cosv - al;
                const float t = ALPHA_ * __expf(-0.5f * d * d);  // SIGMA = 2
                const float o = (c == lb_r[m * 4 + j]) ? al : (t * cosv + t - 1.0f);
                if (ok) out[(size_t)(rb0 + m * 16 + j) * C_ + c] = SCALE_ * o;
            }
    }
}

extern "C" void kernel_launch(void* const* d_in, const int* in_sizes, int n_in,
                              void* d_out, int out_size, void* d_ws, size_t ws_size,
                              hipStream_t stream) {
    const float* inp = (const float*)d_in[0];
    const int*   lab = (const int*)d_in[1];
    const float* w   = (const float*)d_in[2];
    float* out = (float*)d_out;

    char* ws = (char*)d_ws;
    __bf16* xnf  = (__bf16*)ws;                       // 262144 B
    float*  a_lb = (float*)(ws + 262144);             // 1 KiB
    int*    l32  = (int*)(ws + 262144 + 1024);        // 1 KiB

    prep_kernel<<<B_, 64, 0, stream>>>(inp, lab, w, xnf, a_lb, l32);
    gemm_kernel<<<(C_ + BN - 1) / BN, 512, 0, stream>>>(xnf, w, a_lb, l32, out);
}